// Round 5
// baseline (13501.855 us; speedup 1.0000x reference)
//
#include <hip/hip_runtime.h>
#include <math.h>
#include <string.h>

// LSTM: B=256, S=512, I=64, H=256, fp32.
//
// R5: cooperative, fence-free. 256 blocks = 32 row-groups x 8 col-blocks.
// Weights in registers/AGPRs (40/lane). Cross-block h exchange and flags use
// RELAXED agent-scope atomics (sc1 -> MALL-coherent per access) -- NO
// acquire/release, so no per-step buffer_wbl2/buffer_inv full-L2 maintenance
// (R4's 24 us/step stall, diagnosed from VALUBusy 8.2% x 25.8 us).
//
// Per block (16 waves x 64 lanes):
//   wave wv stages ONLY its own k-slices: h-k in [16wv,16wv+16),
//   x-k in [4wv,4wv+4) -> no staging barrier (same-wave DS ordering).
//   lane owns gate-cols gc0=lane (i|f), gc1=64+lane (c|o), col=c0+(lane&31).
//   k-partial dots reduced across waves via LDS atomicAdd into preact[8][128].
//   Update threads (tid<256) do activation+cell update inline.
// 2 __syncthreads per step. Flag protocol: producer posts flags[blk]=s+1
// after (C); consumers poll >= s at top of step s (0xAA poison is negative).

#define BB 256
#define SS 512
#define II 64
#define HH 256
#define KH 16                   // h-k per wave
#define KX 4                    // x-k per wave
#define RPG 8                   // rows per group
#define NGROUP (BB / RPG)       // 32
#define CBPG 8                  // col-blocks per group
#define HCPB (HH / CBPG)        // 32
#define NBLK (NGROUP * CBPG)    // 256
#define HBUF (BB * HH)          // floats per h buffer

#define WS_NEEDED (2 * HBUF * 4 + NBLK * 4)

__device__ __forceinline__ float fast_sigmoid(float v) {
    float e = __expf(-v);
    return __builtin_amdgcn_rcpf(1.0f + e);
}

__device__ __forceinline__ float fast_tanh(float v) {
    v = fminf(fmaxf(v, -15.0f), 15.0f);
    float e = __expf(2.0f * v);
    return (e - 1.0f) * __builtin_amdgcn_rcpf(e + 1.0f);
}

__global__ __launch_bounds__(1024, 4)
void lstm_coop(const float* __restrict__ x,
               const float* __restrict__ wi, const float* __restrict__ ui, const float* __restrict__ bi,
               const float* __restrict__ wf, const float* __restrict__ uf, const float* __restrict__ bf,
               const float* __restrict__ wc, const float* __restrict__ uc, const float* __restrict__ bc,
               const float* __restrict__ wo, const float* __restrict__ uo, const float* __restrict__ bo,
               float* __restrict__ out, float* hglob, int* flags)
{
    __shared__ __align__(16) float hx[RPG][HH + II];    // 10 KB
    __shared__ __align__(16) float preact[RPG][128];    // 4 KB
    __shared__ __align__(16) float cst[RPG][HCPB];      // 1 KB

    const int tid  = threadIdx.x;
    const int wv   = tid >> 6;
    const int lane = tid & 63;

    const int blk   = blockIdx.x;
    const int xcd   = blk & 7;
    const int inner = blk >> 3;
    const int group = xcd * 4 + (inner & 3);     // 0..31
    const int cb    = inner >> 2;                // 0..7
    const int b0 = group * RPG;
    const int c0 = cb * HCPB;

    // lane's two gate-columns
    const int col  = c0 + (lane & 31);
    const int gsel = lane >> 5;
    const float* U0 = gsel ? uf : ui;            // gc0: i | f
    const float* W0 = gsel ? wf : wi;
    const float* U1 = gsel ? uo : uc;            // gc1: c | o
    const float* W1 = gsel ? wo : wc;

    const int k0h = wv * KH;                     // this wave's h k-slice
    const int k0x = wv * KX;                     // this wave's x k-slice

    // ---- weight preload: 40 values/lane ----
    float wreg0[KH + KX], wreg1[KH + KX];
    #pragma unroll
    for (int j = 0; j < KH; ++j) {
        wreg0[j] = U0[(size_t)(k0h + j) * HH + col];
        wreg1[j] = U1[(size_t)(k0h + j) * HH + col];
    }
    #pragma unroll
    for (int j = 0; j < KX; ++j) {
        wreg0[KH + j] = W0[(size_t)(k0x + j) * HH + col];
        wreg1[KH + j] = W1[(size_t)(k0x + j) * HH + col];
    }

    // update-phase biases (valid for tid<256; harmless otherwise)
    const int uh = tid & 31;
    const float bI = bi[c0 + uh], bF = bf[c0 + uh];
    const float bC = bc[c0 + uh], bO = bo[c0 + uh];

    // staging identity: lane -> (row, 8B-chunk) of this wave's h slice
    const int r8 = lane >> 3, j8 = lane & 7;

    unsigned long long* hgu = reinterpret_cast<unsigned long long*>(hglob);

    // ---- init LDS ----
    (&preact[0][0])[tid] = 0.0f;                 // 1024 = 8*128
    if (tid < RPG * HCPB) (&cst[0][0])[tid] = 0.0f;
    __syncthreads();

    for (int s = 0; s < SS; ++s) {
        // ---- stage own h slice (zeros at s=0) ----
        if (s == 0) {
            float2 z; z.x = 0.0f; z.y = 0.0f;
            *reinterpret_cast<float2*>(&hx[r8][k0h + 2 * j8]) = z;
        } else {
            // poll group's 8 flags >= s (relaxed agent atomics; sc1 -> always fresh)
            const int fi = group * CBPG + (lane & 7);
            while (true) {
                const int fv = __hip_atomic_load(&flags[fi], __ATOMIC_RELAXED,
                                                 __HIP_MEMORY_SCOPE_AGENT);
                if (__all(fv >= s)) break;
                __builtin_amdgcn_s_sleep(2);
            }
            const unsigned long long hv8 = __hip_atomic_load(
                &hgu[(size_t)(s & 1) * (HBUF / 2) + (size_t)(b0 + r8) * (HH / 2)
                     + (k0h >> 1) + j8],
                __ATOMIC_RELAXED, __HIP_MEMORY_SCOPE_AGENT);
            float2 f2;
            memcpy(&f2, &hv8, 8);
            *reinterpret_cast<float2*>(&hx[r8][k0h + 2 * j8]) = f2;
        }
        // ---- stage own x slice (lanes 0..7, one row each) ----
        if (lane < RPG) {
            const float4 xv = *reinterpret_cast<const float4*>(
                &x[(size_t)(b0 + lane) * (SS * II) + (size_t)s * II + k0x]);
            *reinterpret_cast<float4*>(&hx[lane][HH + k0x]) = xv;
        }
        asm volatile("" ::: "memory");   // keep ds_reads below the staging writes

        // ---- partial dots: 8 rows x 2 gate-cols over this wave's k-slice ----
        float acc0[RPG], acc1[RPG];
        #pragma unroll
        for (int r = 0; r < RPG; ++r) { acc0[r] = 0.0f; acc1[r] = 0.0f; }
        #pragma unroll
        for (int r = 0; r < RPG; ++r) {
            #pragma unroll
            for (int q = 0; q < KH / 4; ++q) {
                const float4 hv = *reinterpret_cast<const float4*>(&hx[r][k0h + 4 * q]);
                acc0[r] = fmaf(wreg0[4 * q + 0], hv.x, acc0[r]);
                acc0[r] = fmaf(wreg0[4 * q + 1], hv.y, acc0[r]);
                acc0[r] = fmaf(wreg0[4 * q + 2], hv.z, acc0[r]);
                acc0[r] = fmaf(wreg0[4 * q + 3], hv.w, acc0[r]);
                acc1[r] = fmaf(wreg1[4 * q + 0], hv.x, acc1[r]);
                acc1[r] = fmaf(wreg1[4 * q + 1], hv.y, acc1[r]);
                acc1[r] = fmaf(wreg1[4 * q + 2], hv.z, acc1[r]);
                acc1[r] = fmaf(wreg1[4 * q + 3], hv.w, acc1[r]);
            }
            const float4 xv = *reinterpret_cast<const float4*>(&hx[r][HH + k0x]);
            acc0[r] = fmaf(wreg0[16], xv.x, acc0[r]);
            acc0[r] = fmaf(wreg0[17], xv.y, acc0[r]);
            acc0[r] = fmaf(wreg0[18], xv.z, acc0[r]);
            acc0[r] = fmaf(wreg0[19], xv.w, acc0[r]);
            acc1[r] = fmaf(wreg1[16], xv.x, acc1[r]);
            acc1[r] = fmaf(wreg1[17], xv.y, acc1[r]);
            acc1[r] = fmaf(wreg1[18], xv.z, acc1[r]);
            acc1[r] = fmaf(wreg1[19], xv.w, acc1[r]);
        }
        #pragma unroll
        for (int r = 0; r < RPG; ++r) {
            atomicAdd(&preact[r][lane], acc0[r]);        // gc0 = lane
            atomicAdd(&preact[r][64 + lane], acc1[r]);   // gc1 = 64+lane
        }
        __syncthreads();                                   // (A)

        // ---- activation + cell update, inline in update threads ----
        if (tid < 256) {
            const int r = tid >> 5, h = tid & 31;
            const float pi = preact[r][h];
            const float pf = preact[r][32 + h];
            const float pc = preact[r][64 + h];
            const float po = preact[r][96 + h];
            preact[r][h] = 0.0f; preact[r][32 + h] = 0.0f;
            preact[r][64 + h] = 0.0f; preact[r][96 + h] = 0.0f;
            const float iv = fast_sigmoid(pi + bI);
            const float fv = fast_sigmoid(pf + bF);
            const float gv = fast_tanh(pc + bC);
            const float ov = fast_sigmoid(po + bO);
            const float cnew = fmaf(fv, cst[r][h], iv * gv);
            const float hnew = ov * fast_tanh(cnew);
            cst[r][h] = cnew;
            const size_t orow = (size_t)(b0 + r) * HH + (size_t)(c0 + h);
            out[(size_t)s * (BB * HH) + orow] = hnew;
            __hip_atomic_store(&hglob[(size_t)((s + 1) & 1) * HBUF + orow], hnew,
                               __ATOMIC_RELAXED, __HIP_MEMORY_SCOPE_AGENT);
            if (s == SS - 1) {
                out[(size_t)SS * BB * HH + orow] = hnew;
                out[(size_t)SS * BB * HH + (size_t)BB * HH + orow] = cnew;
            }
        }
        __syncthreads();                                   // (C) vmcnt(0) drained
        if (tid == 0 && s + 1 < SS) {
            __hip_atomic_store(&flags[group * CBPG + cb], s + 1,
                               __ATOMIC_RELAXED, __HIP_MEMORY_SCOPE_AGENT);
        }
    }
}

// ---------------- fallback (batch-partitioned) if ws too small ----------------

#define RR 4
#define NBLK_BP (BB / RR)

__global__ __launch_bounds__(1024, 1)
void lstm_batchpart(const float* __restrict__ x,
                    const float* __restrict__ wi, const float* __restrict__ ui, const float* __restrict__ bi,
                    const float* __restrict__ wf, const float* __restrict__ uf, const float* __restrict__ bf,
                    const float* __restrict__ wc, const float* __restrict__ uc, const float* __restrict__ bc,
                    const float* __restrict__ wo, const float* __restrict__ uo, const float* __restrict__ bo,
                    float* __restrict__ out)
{
    __shared__ float hx[RR][320];
    __shared__ float act[4][RR][HH];
    __shared__ float cst[RR][HH];

    const int tid  = threadIdx.x;
    const int wave = tid >> 6;
    const int lane = tid & 63;
    const int g    = wave & 3;
    const int cg   = wave >> 2;
    const int c    = cg * 64 + lane;
    const int b0 = blockIdx.x * RR;

    const float* Ug = (g == 0) ? ui : (g == 1) ? uf : (g == 2) ? uc : uo;
    const float* Wg = (g == 0) ? wi : (g == 1) ? wf : (g == 2) ? wc : wo;
    const float* Bg = (g == 0) ? bi : (g == 1) ? bf : (g == 2) ? bc : bo;
    const float bias_c = Bg[c];

    {
        int rr2 = tid >> 8, cc = tid & 255;
        hx[rr2][cc]  = 0.0f;
        cst[rr2][cc] = 0.0f;
        if (tid < RR * II) {
            int rr = tid >> 6, ii = tid & 63;
            hx[rr][256 + ii] = x[(size_t)(b0 + rr) * (SS * II) + ii];
        }
    }
    __syncthreads();

    for (int s = 0; s < SS; ++s) {
        float a0 = bias_c, a1 = bias_c, a2 = bias_c, a3 = bias_c;
        #pragma unroll 2
        for (int k = 0; k < HH; k += 4) {
            const float4 h0 = *reinterpret_cast<const float4*>(&hx[0][k]);
            const float4 h1 = *reinterpret_cast<const float4*>(&hx[1][k]);
            const float4 h2 = *reinterpret_cast<const float4*>(&hx[2][k]);
            const float4 h3 = *reinterpret_cast<const float4*>(&hx[3][k]);
            const float w0 = Ug[(size_t)(k + 0) * HH + c];
            const float w1 = Ug[(size_t)(k + 1) * HH + c];
            const float w2 = Ug[(size_t)(k + 2) * HH + c];
            const float w3 = Ug[(size_t)(k + 3) * HH + c];
            a0 = fmaf(w0, h0.x, a0); a0 = fmaf(w1, h0.y, a0);
            a0 = fmaf(w2, h0.z, a0); a0 = fmaf(w3, h0.w, a0);
            a1 = fmaf(w0, h1.x, a1); a1 = fmaf(w1, h1.y, a1);
            a1 = fmaf(w2, h1.z, a1); a1 = fmaf(w3, h1.w, a1);
            a2 = fmaf(w0, h2.x, a2); a2 = fmaf(w1, h2.y, a2);
            a2 = fmaf(w2, h2.z, a2); a2 = fmaf(w3, h2.w, a2);
            a3 = fmaf(w0, h3.x, a3); a3 = fmaf(w1, h3.y, a3);
            a3 = fmaf(w2, h3.z, a3); a3 = fmaf(w3, h3.w, a3);
        }
        #pragma unroll 2
        for (int k = 0; k < II; k += 4) {
            const float4 h0 = *reinterpret_cast<const float4*>(&hx[0][256 + k]);
            const float4 h1 = *reinterpret_cast<const float4*>(&hx[1][256 + k]);
            const float4 h2 = *reinterpret_cast<const float4*>(&hx[2][256 + k]);
            const float4 h3 = *reinterpret_cast<const float4*>(&hx[3][256 + k]);
            const float w0 = Wg[(size_t)(k + 0) * HH + c];
            const float w1 = Wg[(size_t)(k + 1) * HH + c];
            const float w2 = Wg[(size_t)(k + 2) * HH + c];
            const float w3 = Wg[(size_t)(k + 3) * HH + c];
            a0 = fmaf(w0, h0.x, a0); a0 = fmaf(w1, h0.y, a0);
            a0 = fmaf(w2, h0.z, a0); a0 = fmaf(w3, h0.w, a0);
            a1 = fmaf(w0, h1.x, a1); a1 = fmaf(w1, h1.y, a1);
            a1 = fmaf(w2, h1.z, a1); a1 = fmaf(w3, h1.w, a1);
            a2 = fmaf(w0, h2.x, a2); a2 = fmaf(w1, h2.y, a2);
            a2 = fmaf(w2, h2.z, a2); a2 = fmaf(w3, h2.w, a2);
            a3 = fmaf(w0, h3.x, a3); a3 = fmaf(w1, h3.y, a3);
            a3 = fmaf(w2, h3.z, a3); a3 = fmaf(w3, h3.w, a3);
        }

        float v0, v1, v2, v3;
        if (g == 2) {
            v0 = fast_tanh(a0); v1 = fast_tanh(a1);
            v2 = fast_tanh(a2); v3 = fast_tanh(a3);
        } else {
            v0 = fast_sigmoid(a0); v1 = fast_sigmoid(a1);
            v2 = fast_sigmoid(a2); v3 = fast_sigmoid(a3);
        }
        act[g][0][c] = v0;
        act[g][1][c] = v1;
        act[g][2][c] = v2;
        act[g][3][c] = v3;
        __syncthreads();

        {
            const int r2 = tid >> 8, cc = tid & 255;
            const float iv = act[0][r2][cc];
            const float fv = act[1][r2][cc];
            const float gv = act[2][r2][cc];
            const float ov = act[3][r2][cc];
            const float cnew = fmaf(fv, cst[r2][cc], iv * gv);
            const float hnew = ov * fast_tanh(cnew);
            cst[r2][cc] = cnew;
            hx[r2][cc]  = hnew;
            out[(size_t)s * (BB * HH) + (size_t)(b0 + r2) * HH + cc] = hnew;
            if (s == SS - 1) {
                out[(size_t)SS * BB * HH + (size_t)(b0 + r2) * HH + cc] = hnew;
                out[(size_t)SS * BB * HH + (size_t)BB * HH + (size_t)(b0 + r2) * HH + cc] = cnew;
            }
        }
        if (s + 1 < SS && tid < RR * II) {
            int rr = tid >> 6, ii = tid & 63;
            hx[rr][256 + ii] = x[(size_t)(b0 + rr) * (SS * II) + (size_t)(s + 1) * II + ii];
        }
        __syncthreads();
    }
}

extern "C" void kernel_launch(void* const* d_in, const int* in_sizes, int n_in,
                              void* d_out, int out_size, void* d_ws, size_t ws_size,
                              hipStream_t stream) {
    const float* x  = (const float*)d_in[0];
    const float* wi = (const float*)d_in[1];
    const float* ui = (const float*)d_in[2];
    const float* bi = (const float*)d_in[3];
    const float* wf = (const float*)d_in[4];
    const float* uf = (const float*)d_in[5];
    const float* bf = (const float*)d_in[6];
    const float* wc = (const float*)d_in[7];
    const float* uc = (const float*)d_in[8];
    const float* bc = (const float*)d_in[9];
    const float* wo = (const float*)d_in[10];
    const float* uo = (const float*)d_in[11];
    const float* bo = (const float*)d_in[12];
    float* out = (float*)d_out;

    if (ws_size >= (size_t)WS_NEEDED) {
        float* hglob = (float*)d_ws;                       // 2 x B x H
        int*   flags = (int*)((char*)d_ws + (size_t)2 * HBUF * 4);
        lstm_coop<<<NBLK, 1024, 0, stream>>>(
            x, wi, ui, bi, wf, uf, bf, wc, uc, bc, wo, uo, bo, out, hglob, flags);
    } else {
        lstm_batchpart<<<NBLK_BP, 1024, 0, stream>>>(
            x, wi, ui, bi, wf, uf, bf, wc, uc, bc, wo, uo, bo, out);
    }
}

// Round 10
// 6893.015 us; speedup vs baseline: 1.9588x; 1.9588x over previous
//
#include <hip/hip_runtime.h>
#include <math.h>

// LSTM: B=256, S=512, I=64, H=256, fp32.
//
// R10 (= R9 resubmit; design never executed -- 6 consecutive GPU-acquisition
// timeouts): 512 per-step kernels, graph-captured once and replayed. The
// kernel boundary IS the grid barrier: kernel s reads h_{s-1} = out[(s-1)]
// slab, writes h_s = out[s] slab. No flags, no agent atomics, no LDS
// atomics -- R4/R5 measured the in-kernel flag protocol at ~24 us/step of
// stall regardless of fence flavor; kernel-boundary coherence is HW-managed.
//
// Step kernel: grid 256 = 16 row-blocks x 16 col-blocks, 512 thr (8 waves).
// Block tile: [16 batch rows x 16 hcols x 4 gates] = 16 x 64 gate-cols.
//   lane -> (gate = lane>>4, hcol = lane&15), col = hc0 + hcol
//   wave wv -> k-slice [40*wv, 40*wv+40) of [h(256); x(64)]
//   acc[16] rows in registers; weights one dword/lane/k (per-CU weight
//   traffic 80 KB/step = 0.57 us at the measured ~141 GB/s/CU L2 port,
//   overlapped with the 1.07 us FMA issue).
//   h/x reads are wave-uniform addresses; each hprev element is read
//   exactly once per block (no redundancy).
//   8-way cross-wave reduce via plain LDS partials + 1 barrier.
// c state lives in d_ws (256 KB), touched only by the update phase.

#define BB 256
#define SS 512
#define II 64
#define HH 256
#define KTOT (HH + II)          // 320
#define NW 8                    // waves per block
#define KPW (KTOT / NW)         // 40
#define RPB 16                  // rows per block
#define HCPB 16                 // hidden cols per block
#define SLAB (BB * HH)          // floats per h slab

#define WS_NEEDED (BB * HH * 4)

__device__ __forceinline__ float fast_sigmoid(float v) {
    float e = __expf(-v);
    return __builtin_amdgcn_rcpf(1.0f + e);
}

__device__ __forceinline__ float fast_tanh(float v) {
    v = fminf(fmaxf(v, -15.0f), 15.0f);
    float e = __expf(2.0f * v);
    return (e - 1.0f) * __builtin_amdgcn_rcpf(e + 1.0f);
}

__global__ __launch_bounds__(512, 2)
void lstm_step(const float* __restrict__ x,
               const float* __restrict__ wi, const float* __restrict__ ui, const float* __restrict__ bi,
               const float* __restrict__ wf, const float* __restrict__ uf, const float* __restrict__ bf,
               const float* __restrict__ wc, const float* __restrict__ uc, const float* __restrict__ bc,
               const float* __restrict__ wo, const float* __restrict__ uo, const float* __restrict__ bo,
               const float* __restrict__ hprev,   // out + (s-1)*SLAB; dummy at s==0
               float* __restrict__ hout,          // out + s*SLAB
               float* __restrict__ cbuf,          // [B][H] cell state
               float* __restrict__ tail,          // out + SS*SLAB (h_t ++ c_t)
               int s)
{
    __shared__ float part[NW][RPB][64];     // 32 KB partials

    const int tid  = threadIdx.x;
    const int wv   = tid >> 6;
    const int lane = tid & 63;

    const int rb  = blockIdx.x & 15;
    const int cbk = blockIdx.x >> 4;
    const int b0  = rb * RPB;
    const int hc0 = cbk * HCPB;

    const int gl  = lane >> 4;              // gate 0..3
    const int hl  = lane & 15;
    const int col = hc0 + hl;

    const float* U = (gl == 0) ? ui : (gl == 1) ? uf : (gl == 2) ? uc : uo;
    const float* W = (gl == 0) ? wi : (gl == 1) ? wf : (gl == 2) ? wc : wo;

    float acc[RPB];
    #pragma unroll
    for (int r = 0; r < RPB; ++r) acc[r] = 0.0f;

    const int k0 = wv * KPW;

    // ---- k-chunks of 4 over this wave's slice ----
    #pragma unroll 2
    for (int kc = 0; kc < KPW; kc += 4) {
        const int k = k0 + kc;
        if (k < HH) {
            if (s == 0) continue;           // h_{-1} == 0 (uniform branch)
            const float w0 = U[(size_t)(k + 0) * HH + col];
            const float w1 = U[(size_t)(k + 1) * HH + col];
            const float w2 = U[(size_t)(k + 2) * HH + col];
            const float w3 = U[(size_t)(k + 3) * HH + col];
            #pragma unroll
            for (int r = 0; r < RPB; ++r) {
                const float4 hv = *reinterpret_cast<const float4*>(
                    &hprev[(size_t)(b0 + r) * HH + k]);       // wave-uniform addr
                acc[r] = fmaf(w0, hv.x, acc[r]);
                acc[r] = fmaf(w1, hv.y, acc[r]);
                acc[r] = fmaf(w2, hv.z, acc[r]);
                acc[r] = fmaf(w3, hv.w, acc[r]);
            }
        } else {
            const int kx = k - HH;
            const float w0 = W[(size_t)(kx + 0) * HH + col];
            const float w1 = W[(size_t)(kx + 1) * HH + col];
            const float w2 = W[(size_t)(kx + 2) * HH + col];
            const float w3 = W[(size_t)(kx + 3) * HH + col];
            #pragma unroll
            for (int r = 0; r < RPB; ++r) {
                const float4 xv = *reinterpret_cast<const float4*>(
                    &x[(size_t)(b0 + r) * (SS * II) + (size_t)s * II + kx]);  // uniform
                acc[r] = fmaf(w0, xv.x, acc[r]);
                acc[r] = fmaf(w1, xv.y, acc[r]);
                acc[r] = fmaf(w2, xv.z, acc[r]);
                acc[r] = fmaf(w3, xv.w, acc[r]);
            }
        }
    }

    // ---- write partials (consecutive lanes -> consecutive banks) ----
    #pragma unroll
    for (int r = 0; r < RPB; ++r) part[wv][r][lane] = acc[r];
    __syncthreads();

    // ---- update phase: 256 threads, one cell each ----
    if (tid < RPB * HCPB) {
        const int r = tid >> 4, h = tid & 15;
        float pi = 0.f, pf = 0.f, pc = 0.f, po = 0.f;
        #pragma unroll
        for (int w = 0; w < NW; ++w) {
            pi += part[w][r][h];
            pf += part[w][r][16 + h];
            pc += part[w][r][32 + h];
            po += part[w][r][48 + h];
        }
        const int c = hc0 + h;
        const float iv = fast_sigmoid(pi + bi[c]);
        const float fv = fast_sigmoid(pf + bf[c]);
        const float gv = fast_tanh(pc + bc[c]);
        const float ov = fast_sigmoid(po + bo[c]);
        const size_t idx = (size_t)(b0 + r) * HH + c;
        const float cprev = (s == 0) ? 0.0f : cbuf[idx];
        const float cn = fmaf(fv, cprev, iv * gv);
        const float hn = ov * fast_tanh(cn);
        cbuf[idx] = cn;
        hout[idx] = hn;
        if (s == SS - 1) {
            tail[idx] = hn;                 // h_t
            tail[SLAB + idx] = cn;          // c_t
        }
    }
}

// ---------------- fallback (batch-partitioned, proven) if ws too small ----------------

#define RR 4
#define NBLK_BP (BB / RR)

__global__ __launch_bounds__(1024, 1)
void lstm_batchpart(const float* __restrict__ x,
                    const float* __restrict__ wi, const float* __restrict__ ui, const float* __restrict__ bi,
                    const float* __restrict__ wf, const float* __restrict__ uf, const float* __restrict__ bf,
                    const float* __restrict__ wc, const float* __restrict__ uc, const float* __restrict__ bc,
                    const float* __restrict__ wo, const float* __restrict__ uo, const float* __restrict__ bo,
                    float* __restrict__ out)
{
    __shared__ float hx[RR][320];
    __shared__ float act[4][RR][HH];
    __shared__ float cst[RR][HH];

    const int tid  = threadIdx.x;
    const int wave = tid >> 6;
    const int lane = tid & 63;
    const int g    = wave & 3;
    const int cg   = wave >> 2;
    const int c    = cg * 64 + lane;
    const int b0 = blockIdx.x * RR;

    const float* Ug = (g == 0) ? ui : (g == 1) ? uf : (g == 2) ? uc : uo;
    const float* Wg = (g == 0) ? wi : (g == 1) ? wf : (g == 2) ? wc : wo;
    const float* Bg = (g == 0) ? bi : (g == 1) ? bf : (g == 2) ? bc : bo;
    const float bias_c = Bg[c];

    {
        int rr2 = tid >> 8, cc = tid & 255;
        hx[rr2][cc]  = 0.0f;
        cst[rr2][cc] = 0.0f;
        if (tid < RR * II) {
            int rr = tid >> 6, ii = tid & 63;
            hx[rr][256 + ii] = x[(size_t)(b0 + rr) * (SS * II) + ii];
        }
    }
    __syncthreads();

    for (int s = 0; s < SS; ++s) {
        float a0 = bias_c, a1 = bias_c, a2 = bias_c, a3 = bias_c;
        #pragma unroll 2
        for (int k = 0; k < HH; k += 4) {
            const float4 h0 = *reinterpret_cast<const float4*>(&hx[0][k]);
            const float4 h1 = *reinterpret_cast<const float4*>(&hx[1][k]);
            const float4 h2 = *reinterpret_cast<const float4*>(&hx[2][k]);
            const float4 h3 = *reinterpret_cast<const float4*>(&hx[3][k]);
            const float w0 = Ug[(size_t)(k + 0) * HH + c];
            const float w1 = Ug[(size_t)(k + 1) * HH + c];
            const float w2 = Ug[(size_t)(k + 2) * HH + c];
            const float w3 = Ug[(size_t)(k + 3) * HH + c];
            a0 = fmaf(w0, h0.x, a0); a0 = fmaf(w1, h0.y, a0);
            a0 = fmaf(w2, h0.z, a0); a0 = fmaf(w3, h0.w, a0);
            a1 = fmaf(w0, h1.x, a1); a1 = fmaf(w1, h1.y, a1);
            a1 = fmaf(w2, h1.z, a1); a1 = fmaf(w3, h1.w, a1);
            a2 = fmaf(w0, h2.x, a2); a2 = fmaf(w1, h2.y, a2);
            a2 = fmaf(w2, h2.z, a2); a2 = fmaf(w3, h2.w, a2);
            a3 = fmaf(w0, h3.x, a3); a3 = fmaf(w1, h3.y, a3);
            a3 = fmaf(w2, h3.z, a3); a3 = fmaf(w3, h3.w, a3);
        }
        #pragma unroll 2
        for (int k = 0; k < II; k += 4) {
            const float4 h0 = *reinterpret_cast<const float4*>(&hx[0][256 + k]);
            const float4 h1 = *reinterpret_cast<const float4*>(&hx[1][256 + k]);
            const float4 h2 = *reinterpret_cast<const float4*>(&hx[2][256 + k]);
            const float4 h3 = *reinterpret_cast<const float4*>(&hx[3][256 + k]);
            const float w0 = Wg[(size_t)(k + 0) * HH + c];
            const float w1 = Wg[(size_t)(k + 1) * HH + c];
            const float w2 = Wg[(size_t)(k + 2) * HH + c];
            const float w3 = Wg[(size_t)(k + 3) * HH + c];
            a0 = fmaf(w0, h0.x, a0); a0 = fmaf(w1, h0.y, a0);
            a0 = fmaf(w2, h0.z, a0); a0 = fmaf(w3, h0.w, a0);
            a1 = fmaf(w0, h1.x, a1); a1 = fmaf(w1, h1.y, a1);
            a1 = fmaf(w2, h1.z, a1); a1 = fmaf(w3, h1.w, a1);
            a2 = fmaf(w0, h2.x, a2); a2 = fmaf(w1, h2.y, a2);
            a2 = fmaf(w2, h2.z, a2); a2 = fmaf(w3, h2.w, a2);
            a3 = fmaf(w0, h3.x, a3); a3 = fmaf(w1, h3.y, a3);
            a3 = fmaf(w2, h3.z, a3); a3 = fmaf(w3, h3.w, a3);
        }

        float v0, v1, v2, v3;
        if (g == 2) {
            v0 = fast_tanh(a0); v1 = fast_tanh(a1);
            v2 = fast_tanh(a2); v3 = fast_tanh(a3);
        } else {
            v0 = fast_sigmoid(a0); v1 = fast_sigmoid(a1);
            v2 = fast_sigmoid(a2); v3 = fast_sigmoid(a3);
        }
        act[g][0][c] = v0;
        act[g][1][c] = v1;
        act[g][2][c] = v2;
        act[g][3][c] = v3;
        __syncthreads();

        {
            const int r2 = tid >> 8, cc = tid & 255;
            const float iv = act[0][r2][cc];
            const float fv = act[1][r2][cc];
            const float gv = act[2][r2][cc];
            const float ov = act[3][r2][cc];
            const float cnew = fmaf(fv, cst[r2][cc], iv * gv);
            const float hnew = ov * fast_tanh(cnew);
            cst[r2][cc] = cnew;
            hx[r2][cc]  = hnew;
            out[(size_t)s * (BB * HH) + (size_t)(b0 + r2) * HH + cc] = hnew;
            if (s == SS - 1) {
                out[(size_t)SS * BB * HH + (size_t)(b0 + r2) * HH + cc] = hnew;
                out[(size_t)SS * BB * HH + (size_t)BB * HH + (size_t)(b0 + r2) * HH + cc] = cnew;
            }
        }
        if (s + 1 < SS && tid < RR * II) {
            int rr = tid >> 6, ii = tid & 63;
            hx[rr][256 + ii] = x[(size_t)(b0 + rr) * (SS * II) + (size_t)(s + 1) * II + ii];
        }
        __syncthreads();
    }
}

extern "C" void kernel_launch(void* const* d_in, const int* in_sizes, int n_in,
                              void* d_out, int out_size, void* d_ws, size_t ws_size,
                              hipStream_t stream) {
    const float* x  = (const float*)d_in[0];
    const float* wi = (const float*)d_in[1];
    const float* ui = (const float*)d_in[2];
    const float* bi = (const float*)d_in[3];
    const float* wf = (const float*)d_in[4];
    const float* uf = (const float*)d_in[5];
    const float* bf = (const float*)d_in[6];
    const float* wc = (const float*)d_in[7];
    const float* uc = (const float*)d_in[8];
    const float* bc = (const float*)d_in[9];
    const float* wo = (const float*)d_in[10];
    const float* uo = (const float*)d_in[11];
    const float* bo = (const float*)d_in[12];
    float* out = (float*)d_out;

    if (ws_size >= (size_t)WS_NEEDED) {
        float* cbuf = (float*)d_ws;
        float* tail = out + (size_t)SS * SLAB;
        for (int s = 0; s < SS; ++s) {
            // dummy (never-dereferenced, never-written) pointer at s==0 avoids
            // __restrict__ aliasing of hprev with hout
            const float* hp = (s == 0) ? bi : out + (size_t)(s - 1) * SLAB;
            lstm_step<<<256, 512, 0, stream>>>(
                x, wi, ui, bi, wf, uf, bf, wc, uc, bc, wo, uo, bo,
                hp, out + (size_t)s * SLAB, cbuf, tail, s);
        }
    } else {
        lstm_batchpart<<<NBLK_BP, 1024, 0, stream>>>(
            x, wi, ui, bi, wf, uf, bf, wc, uc, bc, wo, uo, bo, out);
    }
}